// Round 1
// baseline (240.975 us; speedup 1.0000x reference)
//
#include <hip/hip_runtime.h>
#include <hip/hip_bf16.h>

#define TB 8
#define TT 2048
#define TC 1024
#define TH 64
#define NQT (TT/64)          // 32 q-tiles per batch
constexpr float SCALE = 0.125f;   // 64^-0.5

typedef __bf16 bf16;
typedef __bf16 bf16x8 __attribute__((ext_vector_type(8)));
typedef float  f32x4  __attribute__((ext_vector_type(4)));

// ---------------------------------------------------------------------------
// Kernel 1: transpose + cast weights: w_{q,k,v}[1024][64] fp32 -> wT[3][64][1024] bf16
// ---------------------------------------------------------------------------
__global__ void prep_wT(const float* __restrict__ wq, const float* __restrict__ wk,
                        const float* __restrict__ wv, bf16* __restrict__ wT) {
    int idx = blockIdx.x * blockDim.x + threadIdx.x;
    if (idx >= 3 * TH * TC) return;
    int wsel = idx / (TH * TC);
    int rem  = idx % (TH * TC);
    int c = rem / TH;          // consecutive threads -> consecutive h: coalesced read
    int h = rem % TH;
    const float* w = (wsel == 0) ? wq : (wsel == 1) ? wk : wv;
    wT[(size_t)wsel * TH * TC + (size_t)h * TC + c] = (bf16)w[(size_t)c * TH + h];
}

// ---------------------------------------------------------------------------
// Kernel 2: QKV projection. Block = 64 rows of M=B*T, 4 waves x 16 rows.
// Computes 192 output cols (q|k|v). Q pre-scaled. K-loop chunks of 32.
// ---------------------------------------------------------------------------
__launch_bounds__(256)
__global__ void proj_qkv(const float* __restrict__ x, const bf16* __restrict__ wT,
                         bf16* __restrict__ Q, bf16* __restrict__ K, bf16* __restrict__ VT) {
    __shared__ bf16 Xlds[64][40];   // row stride 80 B (16B aligned, pads banks)
    const int tid  = threadIdx.x;
    const int wave = tid >> 6;
    const int lane = tid & 63;
    const int quad = lane >> 4;
    const int l16  = lane & 15;
    const int m0   = blockIdx.x * 64;

    f32x4 acc[12];
#pragma unroll
    for (int i = 0; i < 12; i++) acc[i] = f32x4{0.f, 0.f, 0.f, 0.f};

    const int srow  = tid >> 2;   // 0..63
    const int spart = tid & 3;    // 0..3, 8 floats each
    const float* xrow = x + (size_t)(m0 + srow) * TC + spart * 8;

    for (int kc = 0; kc < TC / 32; kc++) {
        __syncthreads();
        // stage x tile 64x32 fp32 -> bf16 LDS
        float4 a0 = ((const float4*)(xrow + kc * 32))[0];
        float4 a1 = ((const float4*)(xrow + kc * 32))[1];
        bf16x8 xb;
        xb[0] = (bf16)a0.x; xb[1] = (bf16)a0.y; xb[2] = (bf16)a0.z; xb[3] = (bf16)a0.w;
        xb[4] = (bf16)a1.x; xb[5] = (bf16)a1.y; xb[6] = (bf16)a1.z; xb[7] = (bf16)a1.w;
        *(bf16x8*)(&Xlds[srow][spart * 8]) = xb;
        __syncthreads();

        // A fragment: rows = wave*16 + l16, k = quad*8 + j
        bf16x8 af = *(const bf16x8*)(&Xlds[wave * 16 + l16][quad * 8]);
        // B fragments direct from global wT (L2-hot, identical across blocks)
        const bf16* wbase = wT + (size_t)kc * 32 + quad * 8;
#pragma unroll
        for (int g = 0; g < 12; g++) {
            bf16x8 bfar = *(const bf16x8*)(wbase + (size_t)(g * 16 + l16) * TC);
            acc[g] = __builtin_amdgcn_mfma_f32_16x16x32_bf16(af, bfar, acc[g], 0, 0, 0);
        }
    }

    // epilogue: C layout row = quad*4 + r, col = (g&3)*16 + l16
    const int mrow = m0 + wave * 16 + quad * 4;
#pragma unroll
    for (int g = 0; g < 12; g++) {
        int col = (g & 3) * 16 + l16;
#pragma unroll
        for (int r = 0; r < 4; r++) {
            float vv = acc[g][r];
            int m = mrow + r;
            if (g < 4) {
                Q[(size_t)m * TH + col] = (bf16)(vv * SCALE);
            } else if (g < 8) {
                K[(size_t)m * TH + col] = (bf16)vv;
            } else {
                int b = m >> 11;          // m / 2048
                int t = m & 2047;
                VT[((size_t)b * TH + col) * TT + t] = (bf16)vv;
            }
        }
    }
}

// ---------------------------------------------------------------------------
// Kernel 3: causal flash attention. Block = (b, 64-row q-tile), 4 waves x 16 q-rows.
// K-tiles of 64. Q frags in registers; K/VT staged in LDS; P via LDS (C->A layout).
// ---------------------------------------------------------------------------
#define LDP 72   // 64 + 8 pad; row stride 144 B = 16B-aligned

__launch_bounds__(256)
__global__ void attn(const bf16* __restrict__ Q, const bf16* __restrict__ K,
                     const bf16* __restrict__ VT, float* __restrict__ out) {
    __shared__ bf16 Klds[64][LDP];
    __shared__ bf16 Vlds[64][LDP];      // [h][t] (V transposed)
    __shared__ bf16 Plds[4][16][LDP];   // per-wave P tile

    const int tid  = threadIdx.x;
    const int wave = tid >> 6;
    const int lane = tid & 63;
    const int quad = lane >> 4;
    const int l16  = lane & 15;
    const int b    = blockIdx.x >> 5;   // / NQT
    const int qt   = blockIdx.x & 31;
    const int q0   = qt * 64;

    const bf16* Qb = Q  + (size_t)b * TT * TH;
    const bf16* Kb = K  + (size_t)b * TT * TH;
    const bf16* Vb = VT + (size_t)b * TH * TT;

    // Q fragments stay in registers all kernel: row = q0 + wave*16 + l16
    bf16x8 aq[2];
    {
        const bf16* qp = Qb + (size_t)(q0 + wave * 16 + l16) * TH + quad * 8;
        aq[0] = *(const bf16x8*)qp;
        aq[1] = *(const bf16x8*)(qp + 32);
    }

    f32x4 accO[4];
#pragma unroll
    for (int g = 0; g < 4; g++) accO[g] = f32x4{0.f, 0.f, 0.f, 0.f};
    float mI[4], lI[4];
#pragma unroll
    for (int r = 0; r < 4; r++) { mI[r] = -1e30f; lI[r] = 0.f; }

    const int srow = tid >> 3;   // 0..31
    const int sseg = tid & 7;    // 0..7 (8 bf16 each)

    for (int kt = 0; kt <= qt; kt++) {
        const int k0 = kt * 64;
        __syncthreads();   // protect LDS reuse from previous iteration
        // stage K tile [t][h] and VT tile [h][t]
#pragma unroll
        for (int it = 0; it < 2; it++) {
            int row = srow + it * 32;
            uint4 kv = *(const uint4*)(Kb + (size_t)(k0 + row) * TH + sseg * 8);
            *(uint4*)(&Klds[row][sseg * 8]) = kv;
            uint4 vv = *(const uint4*)(Vb + (size_t)row * TT + k0 + sseg * 8);
            *(uint4*)(&Vlds[row][sseg * 8]) = vv;
        }
        __syncthreads();

        // S = (Q*scale) @ K^T  : wave's 16 q-rows x 64 k-cols
        f32x4 s[4];
#pragma unroll
        for (int g = 0; g < 4; g++) {
            f32x4 a = f32x4{0.f, 0.f, 0.f, 0.f};
            bf16x8 b0 = *(const bf16x8*)(&Klds[g * 16 + l16][quad * 8]);
            bf16x8 b1 = *(const bf16x8*)(&Klds[g * 16 + l16][32 + quad * 8]);
            a = __builtin_amdgcn_mfma_f32_16x16x32_bf16(aq[0], b0, a, 0, 0, 0);
            a = __builtin_amdgcn_mfma_f32_16x16x32_bf16(aq[1], b1, a, 0, 0, 0);
            s[g] = a;
        }

        // causal mask on the diagonal tile (C layout: row=quad*4+r, col=g*16+l16)
        if (kt == qt) {
            const int rowbase = q0 + wave * 16 + quad * 4;
#pragma unroll
            for (int g = 0; g < 4; g++) {
                int col = k0 + g * 16 + l16;
#pragma unroll
                for (int r = 0; r < 4; r++)
                    if (col > rowbase + r) s[g][r] = -1e30f;
            }
        }

        // online softmax: row-wise max/sum across 16 lanes (xor<16 stays in quad group)
        float mnew[4], alpha[4];
#pragma unroll
        for (int r = 0; r < 4; r++) {
            float mx = fmaxf(fmaxf(s[0][r], s[1][r]), fmaxf(s[2][r], s[3][r]));
            mx = fmaxf(mx, __shfl_xor(mx, 1));
            mx = fmaxf(mx, __shfl_xor(mx, 2));
            mx = fmaxf(mx, __shfl_xor(mx, 4));
            mx = fmaxf(mx, __shfl_xor(mx, 8));
            mnew[r]  = fmaxf(mI[r], mx);
            alpha[r] = __expf(mI[r] - mnew[r]);
            mI[r]    = mnew[r];
        }
#pragma unroll
        for (int r = 0; r < 4; r++) {
            float rs = 0.f;
#pragma unroll
            for (int g = 0; g < 4; g++) {
                float p = __expf(s[g][r] - mnew[r]);
                s[g][r] = p;
                rs += p;
            }
            rs += __shfl_xor(rs, 1);
            rs += __shfl_xor(rs, 2);
            rs += __shfl_xor(rs, 4);
            rs += __shfl_xor(rs, 8);
            lI[r] = lI[r] * alpha[r] + rs;
        }
        // write P (bf16) to wave-private LDS region; rescale accumulator
#pragma unroll
        for (int g = 0; g < 4; g++) {
#pragma unroll
            for (int r = 0; r < 4; r++) {
                Plds[wave][quad * 4 + r][g * 16 + l16] = (bf16)s[g][r];
                accO[g][r] *= alpha[r];
            }
        }
        __syncthreads();   // P visible (robust; also orders vs Vlds reads)

        // O += P @ V : A = P (16x64) from LDS, B = V via VT tile
#pragma unroll
        for (int c = 0; c < 2; c++) {
            bf16x8 ap = *(const bf16x8*)(&Plds[wave][l16][c * 32 + quad * 8]);
#pragma unroll
            for (int g = 0; g < 4; g++) {
                bf16x8 bv = *(const bf16x8*)(&Vlds[g * 16 + l16][c * 32 + quad * 8]);
                accO[g] = __builtin_amdgcn_mfma_f32_16x16x32_bf16(ap, bv, accO[g], 0, 0, 0);
            }
        }
    }

    // epilogue: out[b][row][h] = accO / l
    const int rowbase = q0 + wave * 16 + quad * 4;
    float* ob = out + (size_t)b * TT * TH;
#pragma unroll
    for (int r = 0; r < 4; r++) {
        float inv = 1.f / lI[r];
#pragma unroll
        for (int g = 0; g < 4; g++)
            ob[(size_t)(rowbase + r) * TH + g * 16 + l16] = accO[g][r] * inv;
    }
}

// ---------------------------------------------------------------------------
extern "C" void kernel_launch(void* const* d_in, const int* in_sizes, int n_in,
                              void* d_out, int out_size, void* d_ws, size_t ws_size,
                              hipStream_t stream) {
    const float* x  = (const float*)d_in[0];
    const float* wq = (const float*)d_in[1];
    const float* wk = (const float*)d_in[2];
    const float* wv = (const float*)d_in[3];

    char* ws = (char*)d_ws;
    bf16* wT = (bf16*)(ws);                         // 3*64*1024*2 = 393216 B
    bf16* Q  = (bf16*)(ws + 393216);                // 16384*64*2  = 2 MB
    bf16* K  = (bf16*)(ws + 2490368);
    bf16* VT = (bf16*)(ws + 4587520);               // total ~6.4 MB
    float* out = (float*)d_out;

    hipLaunchKernelGGL(prep_wT, dim3(768), dim3(256), 0, stream, wq, wk, wv, wT);
    hipLaunchKernelGGL(proj_qkv, dim3(256), dim3(256), 0, stream, x, wT, Q, K, VT);
    hipLaunchKernelGGL(attn, dim3(TB * NQT), dim3(256), 0, stream, Q, K, VT, out);
}

// Round 2
// 186.355 us; speedup vs baseline: 1.2931x; 1.2931x over previous
//
#include <hip/hip_runtime.h>
#include <hip/hip_bf16.h>

#define TB 8
#define TT 2048
#define TC 1024
#define TH 64

typedef __bf16 bf16;
typedef __bf16 bf16x4 __attribute__((ext_vector_type(4)));
typedef __bf16 bf16x8 __attribute__((ext_vector_type(8)));
typedef float  f32x4  __attribute__((ext_vector_type(4)));

// softmax scale folded with log2(e): attn uses exp2 instead of exp
constexpr float QSCALE = 0.125f * 1.44269504088896340736f;

// ---------------------------------------------------------------------------
// Kernel 1: transpose + cast weights: w_{q,k,v}[1024][64] fp32 -> wT[3][64][1024] bf16
// ---------------------------------------------------------------------------
__global__ void prep_wT(const float* __restrict__ wq, const float* __restrict__ wk,
                        const float* __restrict__ wv, bf16* __restrict__ wT) {
    int idx = blockIdx.x * blockDim.x + threadIdx.x;
    if (idx >= 3 * TH * TC) return;
    int wsel = idx / (TH * TC);
    int rem  = idx % (TH * TC);
    int c = rem / TH;
    int h = rem % TH;
    const float* w = (wsel == 0) ? wq : (wsel == 1) ? wk : wv;
    wT[(size_t)wsel * TH * TC + (size_t)h * TC + c] = (bf16)w[(size_t)c * TH + h];
}

// ---------------------------------------------------------------------------
// Kernel 2: QKV projection. One wave per 16 rows of M=B*T; no LDS, no barriers.
// A-frags direct from x (8 contiguous fp32/lane), B-frags from wT (L2-hot).
// Software pipeline: A prefetched 2 iters ahead, B 1 iter ahead.
// ---------------------------------------------------------------------------
__launch_bounds__(64)
__global__ void proj_qkv(const float* __restrict__ x, const bf16* __restrict__ wT,
                         bf16* __restrict__ Q, bf16* __restrict__ K, bf16* __restrict__ VT) {
    const int lane = threadIdx.x;
    const int quad = lane >> 4, l16 = lane & 15;
    const int m0 = blockIdx.x * 16;

    const float* xp = x + (size_t)(m0 + l16) * TC + quad * 8;
    const bf16*  wp = wT + quad * 8;

    f32x4 acc[12];
#pragma unroll
    for (int i = 0; i < 12; i++) acc[i] = f32x4{0.f, 0.f, 0.f, 0.f};

    // prologue: A for kc=0,1 ; B for kc=0
    float4 pa0 = ((const float4*)xp)[0];
    float4 pa1 = ((const float4*)xp)[1];
    float4 qa0 = ((const float4*)(xp + 32))[0];
    float4 qa1 = ((const float4*)(xp + 32))[1];
    bf16x8 bcur[12];
#pragma unroll
    for (int g = 0; g < 12; g++)
        bcur[g] = *(const bf16x8*)(wp + (size_t)(g * 16 + l16) * TC);

#pragma unroll
    for (int kc = 0; kc < 32; kc++) {
        float4 ca0 = pa0, ca1 = pa1;
        pa0 = qa0; pa1 = qa1;
        if (kc + 2 < 32) {
            qa0 = ((const float4*)(xp + (kc + 2) * 32))[0];
            qa1 = ((const float4*)(xp + (kc + 2) * 32))[1];
        }
        bf16x8 cb[12];
#pragma unroll
        for (int g = 0; g < 12; g++) cb[g] = bcur[g];
        if (kc + 1 < 32) {
#pragma unroll
            for (int g = 0; g < 12; g++)
                bcur[g] = *(const bf16x8*)(wp + (size_t)(g * 16 + l16) * TC + (kc + 1) * 32);
        }
        bf16x8 af;
        af[0] = (bf16)ca0.x; af[1] = (bf16)ca0.y; af[2] = (bf16)ca0.z; af[3] = (bf16)ca0.w;
        af[4] = (bf16)ca1.x; af[5] = (bf16)ca1.y; af[6] = (bf16)ca1.z; af[7] = (bf16)ca1.w;
#pragma unroll
        for (int g = 0; g < 12; g++)
            acc[g] = __builtin_amdgcn_mfma_f32_16x16x32_bf16(af, cb[g], acc[g], 0, 0, 0);
    }

    // epilogue: C layout row = quad*4+r, col = (g&3)*16 + l16
    const int mrow = m0 + quad * 4;
#pragma unroll
    for (int g = 0; g < 12; g++) {
        int col = (g & 3) * 16 + l16;
#pragma unroll
        for (int r = 0; r < 4; r++) {
            float vv = acc[g][r];
            int m = mrow + r;
            if (g < 4) {
                Q[(size_t)m * TH + col] = (bf16)(vv * QSCALE);
            } else if (g < 8) {
                K[(size_t)m * TH + col] = (bf16)vv;
            } else {
                int b = m >> 11, t = m & 2047;
                VT[((size_t)b * TH + col) * TT + t] = (bf16)vv;
            }
        }
    }
}

// ---------------------------------------------------------------------------
// Kernel 3: causal flash attention, transposed-score formulation.
// Block = (b, 16-row q-chunk), 4 waves split the k-tiles (stride-4), merge at end.
// St = K_tile @ Q^T (A=K rows, B=Q rows: all frags contiguous global loads).
// P C->A transform via per-wave LDS ping-pong, __threadfence_block ordering.
// ---------------------------------------------------------------------------
#define LDP 72
#define NW 4

__launch_bounds__(256)
__global__ void attn(const bf16* __restrict__ Q, const bf16* __restrict__ K,
                     const bf16* __restrict__ VT, float* __restrict__ out) {
    __shared__ __align__(16) union SM {
        bf16 P[NW][2][16][LDP];                                  // 18432 B
        struct { float O[NW][16][68]; float M[NW][16]; float L[NW][16]; } mg;
    } sm;

    const int tid  = threadIdx.x;
    const int wv   = tid >> 6;
    const int lane = tid & 63;
    const int quad = lane >> 4, l16 = lane & 15;
    const int b  = blockIdx.x & 7;
    const int rt = 127 - (blockIdx.x >> 3);   // long blocks launch first
    const int q0 = rt * 16;
    const int ktmax = rt >> 2;

    const bf16* Qb = Q  + (size_t)b * TT * TH;
    const bf16* Kb = K  + (size_t)b * TT * TH;
    const bf16* Vb = VT + (size_t)b * TH * TT;

    // Q fragments (B-operand role): B[k=h][n=q] = Q[q0+l16][quad*8+j]
    bf16x8 bq0, bq1;
    {
        const bf16* qp = Qb + (size_t)(q0 + l16) * TH + quad * 8;
        bq0 = *(const bf16x8*)qp;
        bq1 = *(const bf16x8*)(qp + 32);
    }

    f32x4 accO[4];
#pragma unroll
    for (int g = 0; g < 4; g++) accO[g] = f32x4{0.f, 0.f, 0.f, 0.f};
    float mI = -1e30f, lI = 0.f;   // softmax state for q = q0 + l16 (replicated per quad)

    int nit = 0;
    for (int kt = wv; kt <= ktmax; kt += NW, nit++) {
        const int k0 = kt * 64;

        // St = K_tile @ Q^T : 64 t-rows x 16 q-cols
        f32x4 s[4];
#pragma unroll
        for (int g = 0; g < 4; g++) {
            const bf16* kp = Kb + (size_t)(k0 + g * 16 + l16) * TH + quad * 8;
            bf16x8 ka0 = *(const bf16x8*)kp;
            bf16x8 ka1 = *(const bf16x8*)(kp + 32);
            f32x4 t = f32x4{0.f, 0.f, 0.f, 0.f};
            t = __builtin_amdgcn_mfma_f32_16x16x32_bf16(ka0, bq0, t, 0, 0, 0);
            t = __builtin_amdgcn_mfma_f32_16x16x32_bf16(ka1, bq1, t, 0, 0, 0);
            s[g] = t;
        }

        // causal mask on diagonal tile: t_local = g*16+quad*4+r, q-k0 = (rt&3)*16+l16
        if (kt == ktmax) {
            const int qrel = ((rt & 3) << 4) + l16;
#pragma unroll
            for (int g = 0; g < 4; g++)
#pragma unroll
                for (int r = 0; r < 4; r++)
                    if (g * 16 + quad * 4 + r > qrel) s[g][r] = -3.0e38f;
        }

        // online softmax over t (16 regs local + quad-axis shuffles)
        float mx = s[0][0];
#pragma unroll
        for (int g = 0; g < 4; g++)
#pragma unroll
            for (int r = 0; r < 4; r++) mx = fmaxf(mx, s[g][r]);
        mx = fmaxf(mx, __shfl_xor(mx, 16));
        mx = fmaxf(mx, __shfl_xor(mx, 32));
        float mnew  = fmaxf(mI, mx);
        float alpha = exp2f(mI - mnew);
        mI = mnew;
        float rs = 0.f;
#pragma unroll
        for (int g = 0; g < 4; g++)
#pragma unroll
            for (int r = 0; r < 4; r++) {
                float p = exp2f(s[g][r] - mnew);
                s[g][r] = p;
                rs += p;
            }
        rs += __shfl_xor(rs, 16);
        rs += __shfl_xor(rs, 32);
        lI = lI * alpha + rs;

        // rescale accO: row q-offset quad*4+r needs alpha of lane l16=quad*4+r
        float arow[4];
#pragma unroll
        for (int r = 0; r < 4; r++) arow[r] = __shfl(alpha, quad * 4 + r);
#pragma unroll
        for (int g = 0; g < 4; g++)
#pragma unroll
            for (int r = 0; r < 4; r++) accO[g][r] *= arow[r];

        // P: St C-layout -> A-layout via per-wave LDS (ping-pong, no barrier)
        const int par = nit & 1;
#pragma unroll
        for (int g = 0; g < 4; g++) {
            bf16x4 pk;
            pk[0] = (bf16)s[g][0]; pk[1] = (bf16)s[g][1];
            pk[2] = (bf16)s[g][2]; pk[3] = (bf16)s[g][3];
            *(bf16x4*)(&sm.P[wv][par][l16][g * 16 + quad * 4]) = pk;
        }
        __threadfence_block();

        // O += P @ V : A = P[q=l16][t], B = VT[h=g*16+l16][t] contiguous
#pragma unroll
        for (int c = 0; c < 2; c++) {
            bf16x8 ap = *(const bf16x8*)(&sm.P[wv][par][l16][c * 32 + quad * 8]);
#pragma unroll
            for (int g = 0; g < 4; g++) {
                const bf16* vp = Vb + (size_t)(g * 16 + l16) * TT + k0 + c * 32 + quad * 8;
                bf16x8 bv = *(const bf16x8*)vp;
                accO[g] = __builtin_amdgcn_mfma_f32_16x16x32_bf16(ap, bv, accO[g], 0, 0, 0);
            }
        }
    }

    // ---- merge the 4 waves' partial (O, m, l) ----
    __syncthreads();   // all waves done with P region before union reuse
#pragma unroll
    for (int g = 0; g < 4; g++)
#pragma unroll
        for (int r = 0; r < 4; r++)
            sm.mg.O[wv][quad * 4 + r][g * 16 + l16] = accO[g][r];
    if (lane < 16) {
        sm.mg.M[wv][lane] = mI;
        sm.mg.L[wv][lane] = lI;
    }
    __syncthreads();

    {
        const int q = tid >> 4;
        const int h = (tid & 15) * 4;
        float gm = sm.mg.M[0][q];
#pragma unroll
        for (int w = 1; w < NW; w++) gm = fmaxf(gm, sm.mg.M[w][q]);
        float denom = 0.f, o0 = 0.f, o1 = 0.f, o2 = 0.f, o3 = 0.f;
#pragma unroll
        for (int w = 0; w < NW; w++) {
            float sc = exp2f(sm.mg.M[w][q] - gm);
            denom += sm.mg.L[w][q] * sc;
            o0 += sm.mg.O[w][q][h + 0] * sc;
            o1 += sm.mg.O[w][q][h + 1] * sc;
            o2 += sm.mg.O[w][q][h + 2] * sc;
            o3 += sm.mg.O[w][q][h + 3] * sc;
        }
        float inv = 1.f / denom;
        float4 res = make_float4(o0 * inv, o1 * inv, o2 * inv, o3 * inv);
        *(float4*)(out + ((size_t)b * TT + q0 + q) * TH + h) = res;
    }
}

// ---------------------------------------------------------------------------
extern "C" void kernel_launch(void* const* d_in, const int* in_sizes, int n_in,
                              void* d_out, int out_size, void* d_ws, size_t ws_size,
                              hipStream_t stream) {
    const float* x  = (const float*)d_in[0];
    const float* wq = (const float*)d_in[1];
    const float* wk = (const float*)d_in[2];
    const float* wv = (const float*)d_in[3];

    char* ws = (char*)d_ws;
    bf16* wT = (bf16*)(ws);                         // 393216 B
    bf16* Q  = (bf16*)(ws + 393216);                // 2 MB
    bf16* K  = (bf16*)(ws + 2490368);               // 2 MB
    bf16* VT = (bf16*)(ws + 4587520);               // 2 MB
    float* out = (float*)d_out;

    hipLaunchKernelGGL(prep_wT, dim3(768), dim3(256), 0, stream, wq, wk, wv, wT);
    hipLaunchKernelGGL(proj_qkv, dim3(1024), dim3(64), 0, stream, x, wT, Q, K, VT);
    hipLaunchKernelGGL(attn, dim3(TB * 128), dim3(256), 0, stream, Q, K, VT, out);
}